// Round 1
// baseline (275.963 us; speedup 1.0000x reference)
//
#include <hip/hip_runtime.h>
#include <hip/hip_bf16.h>

// ModulatedConv2D: B=8, IC=OC=512, K=3, H=W=32
// Factorization: y[b,oc,p] = d[b,oc] * conv( x[b,ic,p] * (RC_CONV*style[b,ic]), conv_w )
// Conv as implicit GEMM per batch: M=oc(512), N=pixels(1024), K=t*512+ic (4608).

#define B_   8
#define IC_  512
#define OC_  512
#define HW_  1024
#define KT_  4608   // 9*512
#define PAD_ 34     // 32 + 2 halo

static constexpr float RC_DENSE = 0.04419417382415922f;   // 1/sqrt(512)
static constexpr float RC_CONV  = 0.014731391274719739f;  // 1/sqrt(4608)

typedef _Float16 half8  __attribute__((ext_vector_type(8)));
typedef float    floatx4 __attribute__((ext_vector_type(4)));

// ---------------- style = w @ (RC_DENSE*dense_w) + dense_b + 1 ----------------
__global__ __launch_bounds__(512) void style_kernel(
    const float* __restrict__ w, const float* __restrict__ dense_w,
    const float* __restrict__ dense_b, float* __restrict__ style) {
  const int b = blockIdx.x, i = threadIdx.x;
  float acc = 0.f;
  for (int j = 0; j < IC_; ++j)
    acc += w[b * IC_ + j] * dense_w[j * IC_ + i];
  style[b * IC_ + i] = acc * RC_DENSE + dense_b[i] + 1.0f;
}

// ---------------- S[ic,oc] = sum_t conv_w[t,ic,oc]^2 ----------------
__global__ __launch_bounds__(512) void s_kernel(
    const float* __restrict__ cw, float* __restrict__ S) {
  const int ic = blockIdx.x, oc = threadIdx.x;
  float s = 0.f;
  for (int t = 0; t < 9; ++t) {
    float v = cw[(t * IC_ + ic) * OC_ + oc];
    s += v * v;
  }
  S[ic * OC_ + oc] = s;
}

// ---------------- d[b,oc] = rsqrt(RC^2 * sum_ic style^2 * S + 1e-8) ----------------
__global__ __launch_bounds__(128) void d_kernel(
    const float* __restrict__ S, const float* __restrict__ style,
    float* __restrict__ dvec) {
  const int b = blockIdx.y, oc = blockIdx.x * 128 + threadIdx.x;
  float s = 0.f;
  for (int ic = 0; ic < IC_; ++ic) {
    float st = style[b * IC_ + ic];
    s += st * st * S[ic * OC_ + oc];
  }
  dvec[b * OC_ + oc] = rsqrtf(s * (RC_CONV * RC_CONV) + 1e-8f);
}

// ---------------- Wt[oc][k] = (f16) conv_w[k*512 + oc]  (tiled transpose) ----------------
__global__ __launch_bounds__(256) void wt_kernel(
    const float* __restrict__ cw, _Float16* __restrict__ Wt) {
  const int k0 = blockIdx.x * 32, oc0 = blockIdx.y * 32;
  const int sub = threadIdx.x & 31, grp = threadIdx.x >> 5;  // 8 groups
  __shared__ _Float16 t[32][33];
  for (int r = 0; r < 4; ++r) {
    int kk = r * 8 + grp;
    t[kk][sub] = (_Float16)cw[(k0 + kk) * OC_ + oc0 + sub];  // coalesced in oc
  }
  __syncthreads();
  for (int r = 0; r < 4; ++r) {
    int oo = r * 8 + grp;
    Wt[(size_t)(oc0 + oo) * KT_ + k0 + sub] = t[sub][oo];    // coalesced in k
  }
}

// ---------------- xsp[b][r][c][ic] = (f16) x * RC_CONV*style, zero-padded ----------------
__global__ __launch_bounds__(256) void xsp_kernel(
    const float* __restrict__ x, const float* __restrict__ style,
    _Float16* __restrict__ xsp) {
  const int b = blockIdx.z, h = blockIdx.x, ic0 = blockIdx.y * 32;
  const int sub = threadIdx.x & 31, grp = threadIdx.x >> 5;
  __shared__ _Float16 t[32][33];  // [w][ic_local]
  for (int r = 0; r < 4; ++r) {
    int icl = r * 8 + grp, ic = ic0 + icl;
    float v = x[((size_t)(b * IC_ + ic) * 32 + h) * 32 + sub] *
              (style[b * IC_ + ic] * RC_CONV);
    t[sub][icl] = (_Float16)v;
  }
  __syncthreads();
  for (int r = 0; r < 4; ++r) {
    int ww = r * 8 + grp;
    xsp[(((size_t)b * PAD_ + h + 1) * PAD_ + (ww + 1)) * IC_ + ic0 + sub] = t[ww][sub];
  }
}

// ---------------- conv: implicit GEMM, 64x64 C-tile, 4 waves x (2x2) 16x16x32 f16 MFMA ----
// A[m][k]: lane m=lane&15, k=(lane>>4)*8+j (16B contiguous in Wt[oc][k])
// B[k][n]: lane n=lane&15, k=(lane>>4)*8+j (16B contiguous in xsp[..][ic])
// C/D:     col=lane&15 (pixel), row=(lane>>4)*4+reg (oc)
__global__ __launch_bounds__(256) void conv_kernel(
    const _Float16* __restrict__ Wt,   // [512][4608]
    const _Float16* __restrict__ xsp,  // [8][34][34][512]
    const float* __restrict__ dvec,    // [8][512]
    float* __restrict__ out) {         // [8][512][32][32]
  const int bx = blockIdx.x;           // pixel tile: rows h0=2*bx
  const int by = blockIdx.y;           // oc tile: oc0 = 64*by
  const int b  = blockIdx.z;
  const int tid = threadIdx.x;
  const int lane = tid & 63, wid = tid >> 6;
  const int wm = wid & 1, wn = wid >> 1;     // wave quadrant in 64x64 tile
  const int m = lane & 15, q = lane >> 4;
  const int h0 = bx * 2, oc0 = by * 64;

  __shared__ __align__(16) _Float16 Xl[136 * 32];  // [4 rows x 34 cols][32 ic]

  floatx4 acc[2][2] = {};

  const _Float16* xb = xsp + (size_t)b * PAD_ * PAD_ * IC_;

  for (int icb = 0; icb < 16; ++icb) {
    const int ic0 = icb * 32;
    __syncthreads();
    // stage 4x34 padded pixels x 32 ic = 544 x 16B vectors
    for (int v = tid; v < 544; v += 256) {
      int pix = v >> 2, qq = (v & 3) * 8;
      int rr = pix / 34, c = pix - rr * 34;
      const _Float16* src = xb + ((size_t)(h0 + rr) * PAD_ + c) * IC_ + ic0 + qq;
      *(uint4*)(&Xl[pix * 32 + qq]) = *(const uint4*)src;
    }
    __syncthreads();

    const _Float16* wbase = Wt + (size_t)(oc0 + wm * 32 + m) * KT_ + ic0 + q * 8;
    for (int t = 0; t < 9; ++t) {
      const int kh = t / 3, kw = t - kh * 3;
      half8 a0 = *(const half8*)(wbase + t * 512);
      half8 a1 = *(const half8*)(wbase + t * 512 + 16 * KT_);
      const int pbase = (wn + kh) * PAD_ + m + kw;
      half8 b0 = *(const half8*)(&Xl[pbase * 32 + q * 8]);
      half8 b1 = *(const half8*)(&Xl[(pbase + 16) * 32 + q * 8]);
      acc[0][0] = __builtin_amdgcn_mfma_f32_16x16x32_f16(a0, b0, acc[0][0], 0, 0, 0);
      acc[0][1] = __builtin_amdgcn_mfma_f32_16x16x32_f16(a0, b1, acc[0][1], 0, 0, 0);
      acc[1][0] = __builtin_amdgcn_mfma_f32_16x16x32_f16(a1, b0, acc[1][0], 0, 0, 0);
      acc[1][1] = __builtin_amdgcn_mfma_f32_16x16x32_f16(a1, b1, acc[1][1], 0, 0, 0);
    }
  }

  // epilogue: y = acc * d[b,oc]
  for (int ms = 0; ms < 2; ++ms) {
    const int ocb = oc0 + wm * 32 + ms * 16 + q * 4;
    for (int r = 0; r < 4; ++r) {
      const float dv = dvec[b * OC_ + ocb + r];
      for (int ns = 0; ns < 2; ++ns) {
        const int p = (h0 + wn) * 32 + ns * 16 + m;
        out[(size_t)(b * OC_ + ocb + r) * HW_ + p] = acc[ms][ns][r] * dv;
      }
    }
  }
}

extern "C" void kernel_launch(void* const* d_in, const int* in_sizes, int n_in,
                              void* d_out, int out_size, void* d_ws, size_t ws_size,
                              hipStream_t stream) {
  const float* x       = (const float*)d_in[0];
  const float* w       = (const float*)d_in[1];
  const float* conv_w  = (const float*)d_in[2];
  const float* dense_w = (const float*)d_in[3];
  const float* dense_b = (const float*)d_in[4];
  float* out = (float*)d_out;

  // workspace layout
  char* ws = (char*)d_ws;
  float*    style = (float*)ws;                                   // 16 KB
  float*    dvec  = (float*)(ws + (16 << 10));                    // 16 KB
  float*    S     = (float*)(ws + (32 << 10));                    // 1 MB
  _Float16* Wt    = (_Float16*)(ws + (32 << 10) + (1 << 20));     // 512*4608*2 = 4718592 B
  _Float16* xsp   = (_Float16*)(ws + (32 << 10) + (1 << 20) + 4718592);  // 8*34*34*512*2 B

  hipMemsetAsync(xsp, 0, (size_t)B_ * PAD_ * PAD_ * IC_ * sizeof(_Float16), stream);

  style_kernel<<<B_, 512, 0, stream>>>(w, dense_w, dense_b, style);
  s_kernel<<<IC_, 512, 0, stream>>>(conv_w, S);
  d_kernel<<<dim3(4, B_), 128, 0, stream>>>(S, style, dvec);
  wt_kernel<<<dim3(KT_ / 32, OC_ / 32), 256, 0, stream>>>(conv_w, Wt);
  xsp_kernel<<<dim3(32, 16, B_), 256, 0, stream>>>(x, style, xsp);
  conv_kernel<<<dim3(16, 8, B_), 256, 0, stream>>>(Wt, xsp, dvec, out);
}

// Round 2
// 215.626 us; speedup vs baseline: 1.2798x; 1.2798x over previous
//
#include <hip/hip_runtime.h>
#include <hip/hip_bf16.h>

// ModulatedConv2D: B=8, IC=OC=512, K=3, H=W=32
// y[b,oc,p] = d[b,oc] * conv( x[b,ic,p] * (RC_CONV*style[b,ic]), conv_w )
// Conv as implicit GEMM: M=oc(512), N=pixels(1024/batch), K=t*512+ic (4608).

#define B_   8
#define IC_  512
#define OC_  512
#define HW_  1024
#define KT_  4608   // 9*512
#define PAD_ 34     // 32 + 2 halo

static constexpr float RC_DENSE = 0.04419417382415922f;   // 1/sqrt(512)
static constexpr float RC_CONV  = 0.014731391274719739f;  // 1/sqrt(4608)

typedef _Float16 half8  __attribute__((ext_vector_type(8)));
typedef float    floatx4 __attribute__((ext_vector_type(4)));

// ---------------- style = w @ (RC_DENSE*dense_w) + dense_b + 1 ----------------
__global__ __launch_bounds__(512) void style_kernel(
    const float* __restrict__ w, const float* __restrict__ dense_w,
    const float* __restrict__ dense_b, float* __restrict__ style) {
  const int b = blockIdx.x, i = threadIdx.x;
  float acc = 0.f;
  for (int j = 0; j < IC_; ++j)
    acc += w[b * IC_ + j] * dense_w[j * IC_ + i];
  style[b * IC_ + i] = acc * RC_DENSE + dense_b[i] + 1.0f;
}

// ------- fused: Wt[oc][k] = (f16)cw[k][oc]  AND  S[ic][oc] = sum_t cw^2 -------
__global__ __launch_bounds__(256) void wts_kernel(
    const float* __restrict__ cw, _Float16* __restrict__ Wt,
    float* __restrict__ S) {
  const int ic0 = blockIdx.x * 32, oc0 = blockIdx.y * 32;
  const int sub = threadIdx.x & 31, grp = threadIdx.x >> 5;  // 8 groups
  __shared__ _Float16 tl[32][33];
  float sq[4] = {0.f, 0.f, 0.f, 0.f};
  for (int t = 0; t < 9; ++t) {
    float v[4];
    for (int r = 0; r < 4; ++r) {
      int icl = r * 8 + grp;
      v[r] = cw[(size_t)(t * IC_ + ic0 + icl) * OC_ + oc0 + sub];  // coalesced in oc
      sq[r] += v[r] * v[r];
    }
    __syncthreads();
    for (int r = 0; r < 4; ++r) tl[r * 8 + grp][sub] = (_Float16)v[r];
    __syncthreads();
    for (int r = 0; r < 4; ++r) {
      int oo = r * 8 + grp;
      Wt[(size_t)(oc0 + oo) * KT_ + t * IC_ + ic0 + sub] = tl[sub][oo];  // coalesced in k
    }
  }
  for (int r = 0; r < 4; ++r)
    S[(size_t)(ic0 + r * 8 + grp) * OC_ + oc0 + sub] = sq[r];
}

// ---------------- d[b,oc] = rsqrt(RC^2 * sum_ic style^2 * S + 1e-8) ----------------
__global__ __launch_bounds__(128) void d_kernel(
    const float* __restrict__ S, const float* __restrict__ style,
    float* __restrict__ dvec) {
  const int b = blockIdx.y, oc = blockIdx.x * 128 + threadIdx.x;
  float s = 0.f;
  for (int ic = 0; ic < IC_; ++ic) {
    float st = style[b * IC_ + ic];
    s += st * st * S[ic * OC_ + oc];
  }
  dvec[b * OC_ + oc] = rsqrtf(s * (RC_CONV * RC_CONV) + 1e-8f);
}

// ------- xsp[b][r][c][ic] = (f16) x * RC_CONV*style, writes its own zero pad -------
__global__ __launch_bounds__(256) void xsp_kernel(
    const float* __restrict__ x, const float* __restrict__ style,
    _Float16* __restrict__ xsp) {
  const int b = blockIdx.z, h = blockIdx.x, ic0 = blockIdx.y * 32;
  const int sub = threadIdx.x & 31, grp = threadIdx.x >> 5;
  __shared__ _Float16 tl[32][33];  // [w][ic_local]
  for (int r = 0; r < 4; ++r) {
    int icl = r * 8 + grp, ic = ic0 + icl;
    float v = x[((size_t)(b * IC_ + ic) * 32 + h) * 32 + sub] *
              (style[b * IC_ + ic] * RC_CONV);
    tl[sub][icl] = (_Float16)v;
  }
  __syncthreads();
  _Float16* rowp = xsp + (((size_t)b * PAD_ + h + 1) * PAD_) * IC_ + ic0;
  for (int r = 0; r < 4; ++r) {
    int ww = r * 8 + grp;
    rowp[(size_t)(ww + 1) * IC_ + sub] = tl[ww][sub];
  }
  // zero pad: cols 0 and 33 of this row
  if (threadIdx.x < 64) {
    int col = (threadIdx.x >> 5) ? 33 : 0;
    rowp[(size_t)col * IC_ + (threadIdx.x & 31)] = (_Float16)0.f;
  }
  // zero pad: full rows 0 / 33
  if (h == 0) {
    _Float16* r0 = xsp + ((size_t)b * PAD_ * PAD_) * IC_ + ic0;
    for (int i = threadIdx.x; i < PAD_ * 32; i += 256)
      r0[(size_t)(i >> 5) * IC_ + (i & 31)] = (_Float16)0.f;
  }
  if (h == 31) {
    _Float16* r33 = xsp + (((size_t)b * PAD_ + 33) * PAD_) * IC_ + ic0;
    for (int i = threadIdx.x; i < PAD_ * 32; i += 256)
      r33[(size_t)(i >> 5) * IC_ + (i & 31)] = (_Float16)0.f;
  }
}

// ---- conv: implicit GEMM, 64oc x 128pix C-tile, 4 waves, per-wave 2x4 frags ----
// LDS X layout swizzled [r(6)][q(4)][c(34)][8 halfs]: conflict-free b128 r/w.
// A preloaded per icb into regs (18 x half8) from Wt (L1/L2 resident).
__global__ __launch_bounds__(256, 2) void conv_kernel(
    const _Float16* __restrict__ Wt,   // [512][4608]
    const _Float16* __restrict__ xsp,  // [8][34][34][512]
    const float* __restrict__ dvec,    // [8][512]
    float* __restrict__ out) {         // [8][512][32][32]
  const int bx = blockIdx.x;           // pixel tile: rows h0 = 4*bx
  const int by = blockIdx.y;           // oc tile: oc0 = 64*by
  const int b  = blockIdx.z;
  const int tid = threadIdx.x;
  const int lane = tid & 63, wid = tid >> 6;
  const int wm = wid & 1, wn = wid >> 1;   // wave: wm = oc half (32), wn = pix half (64)
  const int ln = lane & 15, q = lane >> 4;
  const int h0 = bx * 4, oc0 = by * 64 + wm * 32;

  __shared__ __align__(16) _Float16 Xl[6 * 4 * 34 * 8];  // 13056 B

  floatx4 acc[2][4] = {};
  const _Float16* xb = xsp + (size_t)b * PAD_ * PAD_ * IC_;

  for (int icb = 0; icb < 16; ++icb) {
    const int ic0 = icb * 32;
    __syncthreads();
    // stage 6 rows x 34 cols x 32 ic = 816 x 16B chunks, swizzled
    for (int v = tid; v < 816; v += 256) {
      const int r = v / 136, rem = v - r * 136;
      const int C = rem >> 2, qq = rem & 3;
      const uint4 s = *(const uint4*)(xb + ((size_t)(h0 + r) * PAD_ + C) * IC_ + ic0 + qq * 8);
      *(uint4*)&Xl[(((r * 4 + qq) * 34) + C) * 8] = s;
    }
    // preload A fragments for all 9 taps (independent loads, deep pipeline)
    half8 a[2][9];
#pragma unroll
    for (int ms = 0; ms < 2; ++ms) {
      const _Float16* wp = Wt + (size_t)(oc0 + ms * 16 + ln) * KT_ + ic0 + q * 8;
#pragma unroll
      for (int t = 0; t < 9; ++t) a[ms][t] = *(const half8*)(wp + t * IC_);
    }
    __syncthreads();
#pragma unroll
    for (int t = 0; t < 9; ++t) {
      const int kh = t / 3, kw = t - kh * 3;
#pragma unroll
      for (int ns = 0; ns < 4; ++ns) {
        const int row = wn * 2 + (ns >> 1), col0 = (ns & 1) * 16;
        half8 bf = *(const half8*)&Xl[((((row + kh) * 4 + q) * 34) + col0 + kw + ln) * 8];
        acc[0][ns] = __builtin_amdgcn_mfma_f32_16x16x32_f16(a[0][t], bf, acc[0][ns], 0, 0, 0);
        acc[1][ns] = __builtin_amdgcn_mfma_f32_16x16x32_f16(a[1][t], bf, acc[1][ns], 0, 0, 0);
      }
    }
  }

  // epilogue: y = acc * d[b,oc];  D: col(pix)=ln, row(oc)=q*4+r
#pragma unroll
  for (int ms = 0; ms < 2; ++ms) {
    const int ocb = oc0 + ms * 16 + q * 4;
#pragma unroll
    for (int r = 0; r < 4; ++r) {
      const float dv = dvec[b * OC_ + ocb + r];
      float* op = out + (size_t)(b * OC_ + ocb + r) * HW_ + h0 * 32;
#pragma unroll
      for (int ns = 0; ns < 4; ++ns)
        op[wn * 64 + ns * 16 + ln] = acc[ms][ns][r] * dv;
    }
  }
}

extern "C" void kernel_launch(void* const* d_in, const int* in_sizes, int n_in,
                              void* d_out, int out_size, void* d_ws, size_t ws_size,
                              hipStream_t stream) {
  const float* x       = (const float*)d_in[0];
  const float* w       = (const float*)d_in[1];
  const float* conv_w  = (const float*)d_in[2];
  const float* dense_w = (const float*)d_in[3];
  const float* dense_b = (const float*)d_in[4];
  float* out = (float*)d_out;

  char* ws = (char*)d_ws;
  float*    style = (float*)ws;                                   // 16 KB
  float*    dvec  = (float*)(ws + (16 << 10));                    // 16 KB
  float*    S     = (float*)(ws + (32 << 10));                    // 1 MB
  _Float16* Wt    = (_Float16*)(ws + (32 << 10) + (1 << 20));     // 4718592 B
  _Float16* xsp   = (_Float16*)(ws + (32 << 10) + (1 << 20) + 4718592);  // 8*34*34*512*2 B

  wts_kernel<<<dim3(16, 16), 256, 0, stream>>>(conv_w, Wt, S);
  style_kernel<<<B_, 512, 0, stream>>>(w, dense_w, dense_b, style);
  d_kernel<<<dim3(4, B_), 128, 0, stream>>>(S, style, dvec);
  xsp_kernel<<<dim3(32, 16, B_), 256, 0, stream>>>(x, style, xsp);
  conv_kernel<<<dim3(8, 8, B_), 256, 0, stream>>>(Wt, xsp, dvec, out);
}

// Round 4
// 151.235 us; speedup vs baseline: 1.8247x; 1.4258x over previous
//
#include <hip/hip_runtime.h>
#include <stdint.h>

// ModulatedConv2D: B=8, IC=OC=512, K=3, H=W=32
// y[b,oc,p] = d[b,oc] * conv( x[b,ic,p] * (RC_CONV*style[b,ic]), conv_w )
// Conv: implicit GEMM, 32x32x16 f16 MFMA. A (weights) in registers from
// fragment-ordered global (prefetched 1 icb ahead); X double-buffered in LDS
// via global_load_lds, fragment-ordered (no pad, conflict-free b128).

#define B_   8
#define IC_  512
#define OC_  512

static constexpr float RC_DENSE = 0.04419417382415922f;   // 1/sqrt(512)
static constexpr float RC_CONV  = 0.014731391274719739f;  // 1/sqrt(4608)

typedef _Float16 half8    __attribute__((ext_vector_type(8)));
typedef float    floatx16 __attribute__((ext_vector_type(16)));

// async global->LDS, 16B per lane; LDS dest = wave-uniform base + lane*16
__device__ __forceinline__ void g2l(const void* g, void* l) {
  __builtin_amdgcn_global_load_lds(
      (const __attribute__((address_space(1))) void*)g,
      (__attribute__((address_space(3))) void*)l, 16, 0, 0);
}

// ---- Wtf[by][icb][t 9][kk 2][kq 2][oc 64][8 halfs] (f16) and S[ic][oc] ----
__global__ __launch_bounds__(256) void wts_kernel(
    const float* __restrict__ cw, _Float16* __restrict__ Wtf,
    float* __restrict__ S) {
  const int by = blockIdx.x, icb = blockIdx.y;
  const int oc0 = by * 64, ic0 = icb * 32;
  const int oc = threadIdx.x & 63, g = threadIdx.x >> 6;
  __shared__ _Float16 LA[18432];
  float sq[8] = {};
  for (int m = 0; m < 72; ++m) {
    int r = g + 4 * m;                 // k-row within 288 (t*32 + icl)
    int t = r >> 5, icl = r & 31;
    float v = cw[(size_t)(t * IC_ + ic0 + icl) * OC_ + oc0 + oc];  // 64-contig
    sq[m & 7] += v * v;
    int kk = (icl >> 4) & 1, kq2 = (icl >> 3) & 1, j = icl & 7;
    LA[(((t * 2 + kk) * 2 + kq2) * 64 + oc) * 8 + j] = (_Float16)v;
  }
  for (int s2 = 0; s2 < 8; ++s2)
    S[(size_t)(ic0 + g + 4 * s2) * OC_ + oc0 + oc] = sq[s2];
  __syncthreads();
  _Float16* dst = Wtf + (size_t)(by * 16 + icb) * 18432;
  for (int i = 0; i < 9; ++i) {        // 2304 chunks, coalesced b128
    int c = i * 256 + threadIdx.x;
    *(half8*)(dst + (size_t)c * 8) = *(const half8*)&LA[c * 8];
  }
}

// ---- sm[b][ic] = (w@(RC_DENSE*dw) + db + 1)*RC_CONV ; sm2 = sm^2 ----
__global__ __launch_bounds__(256) void style_kernel(
    const float* __restrict__ wv, const float* __restrict__ dw,
    const float* __restrict__ db, float* __restrict__ sm,
    float* __restrict__ sm2) {
  const int b = blockIdx.y;
  const int i = blockIdx.x * 64 + (threadIdx.x & 63);
  const int jg = threadIdx.x >> 6;
  __shared__ float red[4][64];
  float p = 0.f;
  for (int j = jg * 128; j < jg * 128 + 128; ++j)
    p += wv[b * IC_ + j] * dw[(size_t)j * IC_ + i];
  red[jg][threadIdx.x & 63] = p;
  __syncthreads();
  if (threadIdx.x < 64) {
    float s = red[0][threadIdx.x] + red[1][threadIdx.x] +
              red[2][threadIdx.x] + red[3][threadIdx.x];
    s = s * RC_DENSE + db[i] + 1.0f;
    float v = s * RC_CONV;
    sm[b * IC_ + i] = v;
    sm2[b * IC_ + i] = v * v;
  }
}

// ---- dvec[b][oc] = rsqrt(sum_ic sm2*S + 1e-8)  (RC^2 folded into sm2) ----
__global__ __launch_bounds__(256) void d_kernel(
    const float* __restrict__ S, const float* __restrict__ sm2,
    float* __restrict__ dvec) {
  const int b = blockIdx.y;
  const int oc = blockIdx.x * 64 + (threadIdx.x & 63);
  const int g = threadIdx.x >> 6;
  __shared__ float red[4][64];
  float p = 0.f;
  for (int ic = g * 128; ic < g * 128 + 128; ++ic)
    p += sm2[b * IC_ + ic] * S[(size_t)ic * OC_ + oc];
  red[g][threadIdx.x & 63] = p;
  __syncthreads();
  if (threadIdx.x < 64) {
    float s = red[0][threadIdx.x] + red[1][threadIdx.x] +
              red[2][threadIdx.x] + red[3][threadIdx.x];
    dvec[b * OC_ + oc] = rsqrtf(s + 1e-8f);
  }
}

// ---- xsp[b][icb 16][r 34][kk 2][kq 2][C 34][8 halfs] = f16(x*sm), padded ----
__global__ __launch_bounds__(256) void xsp_kernel(
    const float* __restrict__ x, const float* __restrict__ sm,
    _Float16* __restrict__ xsp) {
  const int h = blockIdx.x, b = blockIdx.y;
  __shared__ _Float16 Xt[32 * 520];    // [w][512 ic + 8 pad]
  const int tid = threadIdx.x;
  for (int k = 0; k < 16; ++k) {
    int idx = k * 256 + tid;           // 512 ic * 8 w-quads
    int ic = idx >> 3, wc = (idx & 7) * 4;
    float4 v = *(const float4*)&x[((size_t)(b * IC_ + ic) * 32 + h) * 32 + wc];
    float s = sm[b * IC_ + ic];
    Xt[(wc + 0) * 520 + ic] = (_Float16)(v.x * s);
    Xt[(wc + 1) * 520 + ic] = (_Float16)(v.y * s);
    Xt[(wc + 2) * 520 + ic] = (_Float16)(v.z * s);
    Xt[(wc + 3) * 520 + ic] = (_Float16)(v.w * s);
  }
  __syncthreads();
  _Float16* xb = xsp + (size_t)b * 16 * 36992;
  const int r = h + 1;
  half8 z = {};
  for (int it = 0; it < 9; ++it) {     // 16 icb * 4 kkq * 34 C = 2176 chunks
    int c = it * 256 + tid;
    if (c < 2176) {
      int icb = c / 136, rem = c - 136 * icb, kkq = rem / 34, C = rem - 34 * kkq;
      half8 val = z;
      if (C != 0 && C != 33)
        val = *(const half8*)&Xt[(C - 1) * 520 + icb * 32 + kkq * 8];
      *(half8*)&xb[(size_t)icb * 36992 + (size_t)r * 1088 + kkq * 272 + C * 8] = val;
    }
  }
  if (h == 0 || h == 31) {             // zero top/bottom padded rows
    const int rz = (h == 0) ? 0 : 33;
    for (int it = 0; it < 9; ++it) {
      int c = it * 256 + tid;
      if (c < 2176) {
        int icb = c / 136, rem = c - 136 * icb, kkq = rem / 34, C = rem - 34 * kkq;
        *(half8*)&xb[(size_t)icb * 36992 + (size_t)rz * 1088 + kkq * 272 + C * 8] = z;
      }
    }
  }
}

// ---- conv: block 64oc x 256px (8 rows), grid 4x8x8 = 256 (1 block/CU) ----
// Wave (wm,wn): 32oc x 128px (4 rows). Per icb: 18 A b128 (global, prefetched
// to an[]), 36 X b128 (LDS), 72 MFMA 32x32x16 (2325 cyc/SIMD — the bound).
__global__ __launch_bounds__(256) void conv_kernel(
    const _Float16* __restrict__ Wtf,   // [8 by][16 icb][18432 halfs]
    const _Float16* __restrict__ xsp,   // [8 b][16 icb][34 r][4 kkq][34 C][8]
    const float* __restrict__ dvec,     // [8][512]
    float* __restrict__ out) {          // [8][512][32][32]
  const int bx = blockIdx.x, by = blockIdx.y, b = blockIdx.z;
  const int tid = threadIdx.x, lane = tid & 63, w = tid >> 6;
  const int wm = w & 1, wn = w >> 1;
  const int n = lane & 31, kq = lane >> 5;
  const int h0 = bx * 8;                // padded rows h0 .. h0+9 staged

  __shared__ _Float16 Xb[2][10880];     // 21760 B each, 43520 B total

  const _Float16* gX = xsp + (size_t)b * 16 * 36992 + (size_t)h0 * 1088;
  const _Float16* gA = Wtf + (size_t)(by * 16) * 18432;
  const int aoff = kq * 512 + (wm * 32 + n) * 8;

  // prologue: stage X(0), load A(0)
  for (int i = 0; i < 6; ++i) {
    int c = i * 256 + tid;
    if (c < 1360) g2l(gX + (size_t)c * 8, &Xb[0][c * 8]);
  }
  half8 a[9][2], an[9][2];
#pragma unroll
  for (int t = 0; t < 9; ++t)
#pragma unroll
    for (int kk = 0; kk < 2; ++kk)
      a[t][kk] = *(const half8*)(gA + aoff + (t * 2 + kk) * 1024);

  floatx16 acc[4] = {};
  int cur = 0;
  for (int icb = 0; icb < 16; ++icb) {
    __syncthreads();                    // X(cur) staged & visible
    if (icb < 15) {                     // prefetch icb+1
      const _Float16* gA1 = gA + (size_t)(icb + 1) * 18432 + aoff;
#pragma unroll
      for (int t = 0; t < 9; ++t)
#pragma unroll
        for (int kk = 0; kk < 2; ++kk)
          an[t][kk] = *(const half8*)(gA1 + (t * 2 + kk) * 1024);
      const _Float16* gX1 = gX + (size_t)(icb + 1) * 36992;
      for (int i = 0; i < 6; ++i) {
        int c = i * 256 + tid;
        if (c < 1360) g2l(gX1 + (size_t)c * 8, &Xb[cur ^ 1][c * 8]);
      }
    }
    // compute: X frag at staged row (wn*4+rr), col n+kw, k-half kk
    const _Float16* Xp = &Xb[cur][0] + (wn * 4) * 1088 + kq * 272 + n * 8;
#pragma unroll
    for (int rr = 0; rr < 6; ++rr) {
#pragma unroll
      for (int kw = 0; kw < 3; ++kw) {
#pragma unroll
        for (int kk = 0; kk < 2; ++kk) {
          half8 xv = *(const half8*)(Xp + rr * 1088 + kk * 544 + kw * 8);
#pragma unroll
          for (int kh = 0; kh < 3; ++kh) {
            int pr = rr - kh;
            if (pr >= 0 && pr < 4)
              acc[pr] = __builtin_amdgcn_mfma_f32_32x32x16_f16(
                  a[kh * 3 + kw][kk], xv, acc[pr], 0, 0, 0);
          }
        }
      }
    }
#pragma unroll
    for (int t = 0; t < 9; ++t) { a[t][0] = an[t][0]; a[t][1] = an[t][1]; }
    cur ^= 1;
  }

  // epilogue: D col(px)=lane&31, row(oc)=(rg&3)+8*(rg>>2)+4*kq
  const int oc0 = by * 64 + wm * 32;
  const int r0 = h0 + wn * 4;
#pragma unroll
  for (int rg = 0; rg < 16; ++rg) {
    const int row = (rg & 3) + 8 * (rg >> 2) + 4 * kq;
    const float dv = dvec[b * OC_ + oc0 + row];
    float* op = out + ((size_t)b * OC_ + oc0 + row) * 1024 + r0 * 32 + n;
#pragma unroll
    for (int pr = 0; pr < 4; ++pr)
      op[pr * 32] = acc[pr][rg] * dv;
  }
}

extern "C" void kernel_launch(void* const* d_in, const int* in_sizes, int n_in,
                              void* d_out, int out_size, void* d_ws, size_t ws_size,
                              hipStream_t stream) {
  const float* x       = (const float*)d_in[0];
  const float* w       = (const float*)d_in[1];
  const float* conv_w  = (const float*)d_in[2];
  const float* dense_w = (const float*)d_in[3];
  const float* dense_b = (const float*)d_in[4];
  float* out = (float*)d_out;

  char* ws = (char*)d_ws;
  float*    sm   = (float*)ws;                         // 16 KB
  float*    sm2  = (float*)(ws + (16 << 10));          // 16 KB
  float*    dvec = (float*)(ws + (32 << 10));          // 16 KB
  float*    S    = (float*)(ws + (48 << 10));          // 1 MB
  _Float16* Wtf  = (_Float16*)(ws + (48 << 10) + (1 << 20));           // 4,718,592 B
  _Float16* xsp  = (_Float16*)(ws + (48 << 10) + (1 << 20) + 4718592); // 9,469,952 B

  wts_kernel<<<dim3(8, 16), 256, 0, stream>>>(conv_w, Wtf, S);
  style_kernel<<<dim3(8, B_), 256, 0, stream>>>(w, dense_w, dense_b, sm, sm2);
  xsp_kernel<<<dim3(32, B_), 256, 0, stream>>>(x, sm, xsp);
  d_kernel<<<dim3(8, B_), 256, 0, stream>>>(S, sm2, dvec);
  conv_kernel<<<dim3(4, 8, B_), 256, 0, stream>>>(Wtf, xsp, dvec, out);
}